// Round 10
// baseline (76.860 us; speedup 1.0000x reference)
//
#include <hip/hip_runtime.h>
#include <hip/hip_bf16.h>

#define NV 3889
#define NV3 11667
#define NVP 3904      // ceil(NV/16)*16
#define NVAP 11712    // NVP*3
#define NJC 33        // joints in chain
#define NBB 41        // betas
#define NN 1024       // batch

__device__ const int EXTRA_IDS[6] = {1863, 26, 2124, 150, 3055, 1097};

// ws layout (float offsets)  [R0 layout — verified]
#define WS_SJ    0          // f32 [42][99] (pad)    = 4160  [unused since R10]
#define WS_WPK   4160       // bf16[3904][64]        = 124928 fl
#define WS_SDPK  129088     // bf16[11712][64]       = 374784 fl
#define WS_BPK   503872     // bf16[1024][64]        = 32768 fl
#define WS_APK   536640     // bf16[1024][12][64]    = 393216 fl
#define WS_JTL   929856     // bf16 tiled Jreg [3*128][64][8]          = 98304 fl
#define WS_VTL   1028160    // bf16 tiled vsT [3*64 planes][128][1024] = 12582912 fl
#define WS_SJP   13611072   // f32 [672][100] SJ partials = 67200 fl
// end: 13678272 floats (~55 MB)

typedef __attribute__((ext_vector_type(8))) short short8v;
typedef __attribute__((ext_vector_type(4))) float f32x4;

__device__ __forceinline__ ushort bf16bits(float x) {
  __hip_bfloat16 h = __float2bfloat16(x);
  return *reinterpret_cast<ushort*>(&h);
}

// ---------------- K_prep: vectorized packing + chunked SJ + VTL tail-zero ------
// grid = 672 (SJ) + 366 (SDPK transpose) + 250 (WPK/BPK/JTL) + 576 (VTL zero)
#define PREP_SJ_BLOCKS 672
#define PREP_SD_BLOCKS 366
#define PREP_PK_BLOCKS 250
#define PREP_VZ_BLOCKS 576
__global__ void __launch_bounds__(256) k_prep(
    const float* __restrict__ Jreg, const float* __restrict__ w,
    const float* __restrict__ beta, const float* __restrict__ sd,
    const float* __restrict__ vt, float* __restrict__ ws) {
  int bx = blockIdx.x;
  int t = threadIdx.x;
  if (bx < PREP_SJ_BLOCKS) {
    // ---- SJ partials (chunked: 42 b x 16 chunks) ----
    int bid2 = bx;                    // 0..671
    int b = bid2 >> 4, c = bid2 & 15;
    const float* src = (b < NBB) ? (sd + (size_t)b * NV3) : vt;
    int dv = t / 33, j = t - dv * 33;
    float p0 = 0.f, p1 = 0.f, p2 = 0.f;
    int vbase = c * 244;
    int vend = vbase + 244;
    if (vend > NV) vend = NV;
    if (t < 231) {
      for (int v0 = vbase; v0 < vend; v0 += 7) {
        int v = v0 + dv;
        if (v < vend) {
          float jr = Jreg[v0 * 33 + t];   // contiguous across threads
          p0 += src[v * 3 + 0] * jr;
          p1 += src[v * 3 + 1] * jr;
          p2 += src[v * 3 + 2] * jr;
        }
      }
    }
    __shared__ float sred[7][33][3];
    if (t < 231) { sred[dv][j][0] = p0; sred[dv][j][1] = p1; sred[dv][j][2] = p2; }
    __syncthreads();
    if (t < 99) {
      int jj = t / 3, aa = t - jj * 3;
      float s = 0.f;
#pragma unroll
      for (int d = 0; d < 7; d++) s += sred[d][jj][aa];
      ws[WS_SJP + bid2 * 100 + t] = s;
    }
    return;
  }
  bx -= PREP_SJ_BLOCKS;
  if (bx < PREP_SD_BLOCKS) {
    // ---- SDPK: coalesced read of sd rows -> LDS transpose -> packed store ----
    __shared__ ushort tl[32 * 50];    // 32 va x 50(pad) bs
    int va0 = bx * 32;
    for (int i = t; i < 42 * 32; i += 256) {
      int bs = i >> 5, off = i & 31;
      int va = va0 + off;
      float v = 0.f;
      if (va < NV3) v = (bs < NBB) ? sd[(size_t)bs * NV3 + va] : vt[va];
      tl[off * 50 + bs] = bf16bits(v);
    }
    __syncthreads();
    int va_l = t >> 3, ch = t & 7;    // 32 va x 8 chunks = 256 threads
    short8v pk;
#pragma unroll
    for (int e = 0; e < 8; e++) {
      int bs = ch * 8 + e;
      pk[e] = (bs < 42) ? (short)tl[va_l * 50 + bs] : (short)0;
    }
    *(short8v*)((ushort*)(ws + WS_SDPK) + ((size_t)(va0 + va_l) * 64 + ch * 8)) = pk;
    return;
  }
  bx -= PREP_SD_BLOCKS;
  if (bx < PREP_PK_BLOCKS) {
    int id8 = bx * 256 + t;
    const int R1 = NVP * 64 / 8;       // 31232  Wpk
    const int R3 = NN * 64 / 8;        // 8192   bpk
    short8v pk;
    if (id8 < R1) {
      int u = id8 * 8;
      int v = u >> 6, j0 = u & 63;
#pragma unroll
      for (int e = 0; e < 8; e++) {
        int j = j0 + e;
        float val;
        if (j < NJC)      val = (v < NV) ? w[v * NJC + j] : 0.f;
        else if (j == 41) val = 1.f;               // trans row
        else              val = 0.f;
        pk[e] = (short)bf16bits(val);
      }
      *(short8v*)((ushort*)(ws + WS_WPK) + u) = pk;
      return;
    }
    id8 -= R1;
    if (id8 < R3) {
      int u = id8 * 8;
      int n = u >> 6, bs0 = u & 63;
#pragma unroll
      for (int e = 0; e < 8; e++) {
        int bs = bs0 + e;
        float val = (bs < NBB) ? beta[n * NBB + bs] : (bs == NBB ? 1.f : 0.f);
        pk[e] = (short)bf16bits(val);
      }
      *(short8v*)((ushort*)(ws + WS_BPK) + u) = pk;
      return;
    }
    id8 -= R3;
    {
      // JregTl[tile=jt*128+kc][lane][e]; A-frag: row=lane&15, k=(lane>>4)*8+e
      int u = id8 * 8;                 // id8 < 24576
      int tile = u >> 9, lane = (u >> 3) & 63;
      int jt = tile >> 7, kc = tile & 127;
      int j = jt * 16 + (lane & 15);
      int vb = kc * 32 + ((lane >> 4) << 3);
#pragma unroll
      for (int e = 0; e < 8; e++) {
        int v = vb + e;
        float val = (j < NJC && v < NV) ? Jreg[v * NJC + j] : 0.f;
        pk[e] = (short)bf16bits(val);
      }
      *(short8v*)((ushort*)(ws + WS_JTL) + u) = pk;
      return;
    }
  }
  bx -= PREP_PK_BLOCKS;
  {
    // ---- VTL tail-zero: rows 122..127 of each [128][1024] plane ----
    int id8 = bx * 256 + t;            // [0, 147456)
    int plane = id8 / 768;             // 0..191
    int rem8 = id8 - plane * 768;      // 0..767
    short8v z = {0, 0, 0, 0, 0, 0, 0, 0};
    *(short8v*)((ushort*)(ws + WS_VTL) +
                ((size_t)plane * 131072 + 124928 + rem8 * 8)) = z;
  }
}

// ---------------- K_pose: SJP reduce + J blend + rodrigues + chain -> Apk -------
// 64 blocks x 16 rows x 256 thr. Absorbs k_sjr: each block reduces SJP->LDS
// itself (268 KB L2-hot reads/block, 17 MB aggregate ~0.5us) — deletes the
// k_sjr kernel + one launch gap. Sum orders match old k_sjr/k_pose exactly,
// so Apk is bitwise identical.
__device__ __forceinline__ void get_scal(int r, float e0, float e1, float e2, float e3,
                                         float s[3]) {
  bool leg  = (r >= 7 && r <= 14) || (r >= 17 && r <= 24);
  bool tail = (r >= 25 && r <= 31);
  s[0] = leg ? e1 : (tail ? e2 : 1.f);
  s[1] = leg ? e1 : (tail ? e3 : 1.f);
  s[2] = leg ? e0 : (tail ? e3 : 1.f);
}

__device__ __forceinline__ void rodrigues(const float* th, float R[9]) {
  float tx = th[0], ty = th[1], tz = th[2];
  float ax = tx + 1e-8f, ay = ty + 1e-8f, az = tz + 1e-8f;
  float angle = sqrtf(ax * ax + ay * ay + az * az);
  float inv = 1.f / angle;
  float rx = tx * inv, ry = ty * inv, rz = tz * inv;
  float c = cosf(angle), s = sinf(angle), o = 1.f - c;
  R[0] = c + o * rx * rx;      R[1] = o * rx * ry - s * rz; R[2] = o * rx * rz + s * ry;
  R[3] = o * rx * ry + s * rz; R[4] = c + o * ry * ry;      R[5] = o * ry * rz - s * rx;
  R[6] = o * rx * rz - s * ry; R[7] = o * ry * rz + s * rx; R[8] = c + o * rz * rz;
}

__global__ void __launch_bounds__(256) k_pose(
    const float* __restrict__ beta, const float* __restrict__ theta,
    const float* __restrict__ bls, const float* __restrict__ trans,
    float* __restrict__ ws) {
  int nb = blockIdx.x * 16;          // 64 blocks
  int t = threadIdx.x;
  __shared__ float SJsh[42 * 99];    // 16632 B
  __shared__ float Jsh[16][99];      //  6336 B
  __shared__ float Bsh[16][NJC * 12];// 25344 B  (in-place B -> A during chain)
  // ---- phase1: SJP -> SJsh (identical c-order to old k_sjr) ----
  for (int idx = t; idx < 42 * 99; idx += 256) {
    int b = idx / 99, k = idx - b * 99;
    float s = 0.f;
#pragma unroll
    for (int c = 0; c < 16; c++) s += ws[WS_SJP + (b * 16 + c) * 100 + k];
    SJsh[idx] = s;
  }
  __syncthreads();
  // ---- phase2: J blend for 16 rows (identical b-order to old k_pose) ----
  for (int idx = t; idx < 16 * 99; idx += 256) {
    int row = idx / 99, k = idx - row * 99;
    int n = nb + row;
    float acc = SJsh[NBB * 99 + k];
    const float* bn = beta + n * NBB;
#pragma unroll
    for (int b = 0; b < NBB; b++) acc += bn[b] * SJsh[b * 99 + k];
    Jsh[row][k] = acc;
  }
  __syncthreads();
  // ---- phase3: rodrigues + relative-bone B for (row, joint) = 528 tasks ----
  for (int idx = t; idx < 16 * NJC; idx += 256) {
    int row = idx / NJC, i = idx - row * NJC;
    int n = nb + row;
    float R[9];
    rodrigues(theta + n * 105 + i * 3, R);
    float* B = Bsh[row] + i * 12;
    if (i == 0) {
      B[0] = R[0]; B[1] = R[1]; B[2]  = R[2]; B[3]  = Jsh[row][0];
      B[4] = R[3]; B[5] = R[4]; B[6]  = R[5]; B[7]  = Jsh[row][1];
      B[8] = R[6]; B[9] = R[7]; B[10] = R[8]; B[11] = Jsh[row][2];
    } else {
      float e0 = expf(bls[n * 6 + 0]), e1 = expf(bls[n * 6 + 1]);
      float e2 = expf(bls[n * 6 + 2]), e3 = expf(bls[n * 6 + 3]);
      float si[3], sp[3];
      get_scal(i, e0, e1, e2, e3, si);
      get_scal(i - 1, e0, e1, e2, e3, sp);
#pragma unroll
      for (int r = 0; r < 3; r++) {
        float inv = 1.f / sp[r];
#pragma unroll
        for (int cc = 0; cc < 3; cc++) B[r * 4 + cc] = R[r * 3 + cc] * si[cc] * inv;
        B[r * 4 + 3] = Jsh[row][i * 3 + r] - Jsh[row][(i - 1) * 3 + r];
      }
    }
  }
  __syncthreads();
  // ---- phase4: 16 parallel serial chains; A_i overwrites B_i in place ----
  if (t < 16) {
    int row = t;
    float G[12];
#pragma unroll
    for (int k = 0; k < 12; k++) G[k] = Bsh[row][k];
#pragma unroll
    for (int i = 0; i < NJC; i++) {
      if (i > 0) {
        float b[12];
#pragma unroll
        for (int k = 0; k < 12; k++) b[k] = Bsh[row][i * 12 + k];
        float Gn[12];
#pragma unroll
        for (int r = 0; r < 3; r++) {
#pragma unroll
          for (int cc = 0; cc < 4; cc++) {
            float acc = G[r * 4 + 0] * b[0 * 4 + cc] + G[r * 4 + 1] * b[1 * 4 + cc] +
                        G[r * 4 + 2] * b[2 * 4 + cc];
            if (cc == 3) acc += G[r * 4 + 3];
            Gn[r * 4 + cc] = acc;
          }
        }
#pragma unroll
        for (int k = 0; k < 12; k++) G[k] = Gn[k];
      }
      float jx = Jsh[row][i * 3 + 0], jy = Jsh[row][i * 3 + 1], jz = Jsh[row][i * 3 + 2];
      float* Ai = Bsh[row] + i * 12;   // in-place: B_i already consumed
      Ai[0] = G[0]; Ai[1] = G[1]; Ai[2]  = G[2];
      Ai[3] = G[3] - (G[0] * jx + G[1] * jy + G[2] * jz);
      Ai[4] = G[4]; Ai[5] = G[5]; Ai[6]  = G[6];
      Ai[7] = G[7] - (G[4] * jx + G[5] * jy + G[6] * jz);
      Ai[8] = G[8]; Ai[9] = G[9]; Ai[10] = G[10];
      Ai[11] = G[11] - (G[8] * jx + G[9] * jy + G[10] * jz);
    }
  }
  __syncthreads();
  // ---- phase5: Apk write (short8v): apk[n][c][j] = A[j][c]; j=41 c%4==3 = trans
  for (int idx = t; idx < 16 * 96; idx += 256) {
    int row = idx / 96, r2 = idx - row * 96;
    int c = r2 >> 3, jg = r2 & 7;
    int n = nb + row;
    short8v pk;
#pragma unroll
    for (int e = 0; e < 8; e++) {
      int j = jg * 8 + e;
      float val = 0.f;
      if (j < NJC)                      val = Bsh[row][j * 12 + c];
      else if (j == 41 && (c & 3) == 3) val = trans[n * 3 + (c >> 2)];
      pk[e] = (short)bf16bits(val);
    }
    *(short8v*)((ushort*)(ws + WS_APK) + (size_t)n * 768 + c * 64 + jg * 8) = pk;
  }
}

// ---------------- K_sv: 512 threads, 8 waves share Ash; VT=2; 2 chunks/block ----
// [R0-verified structure: 2 barriers/chunk, vst bf16 tile out for k_jg2]
#define ASH_USH (16 * 12 * 72)        // 13824 ushorts (27.6 KB)
#define VSL2_USH (2 * 16 * 72)        // 2304 ushorts per wave (2 vtiles)

__global__ void __launch_bounds__(512, 4) k_sv(
    const float* __restrict__ ws, ushort* __restrict__ vst,
    float* __restrict__ out) {
  __shared__ __align__(16) ushort lds[ASH_USH + 8 * VSL2_USH];   // 64.5 KB
  int wv = threadIdx.x >> 6, lane = threadIdx.x & 63;
  int g = lane >> 4, c16 = lane & 15;
  int p = blockIdx.x * 8 + wv;         // pair index 0..127
  int pc = p < 122 ? p : 121;
  bool pok = p < 122;
  int vtA = pc * 2, vtB = vtA + 1;
  int vA = vtA * 16 + c16, vB = vtB * 16 + c16;
  int nb0 = blockIdx.y * 32;
  const ushort* Wp = (const ushort*)(ws + WS_WPK);
  const ushort* Sp = (const ushort*)(ws + WS_SDPK);
  const ushort* Bp = (const ushort*)(ws + WS_BPK);
  const ushort* Ap = (const ushort*)(ws + WS_APK);

  // loop-invariant fragments
  short8v wfA0 = *(const short8v*)(Wp + vA * 64 + g * 8);
  short8v wfA1 = *(const short8v*)(Wp + vA * 64 + 32 + g * 8);
  short8v wfB0 = *(const short8v*)(Wp + vB * 64 + g * 8);
  short8v wfB1 = *(const short8v*)(Wp + vB * 64 + 32 + g * 8);
  int vaA = vtA * 48 + c16, vaB = vtB * 48 + c16;

  ushort* vslA = lds + ASH_USH + wv * VSL2_USH;
  ushort* vslB = vslA + 1152;
  bool act = g < 3;
  int hiA = c16 >> 3, hiB = 2 + (c16 >> 3), e8 = c16 & 7;

#pragma unroll 1
  for (int ch = 0; ch < 2; ch++) {
    int nb = nb0 + ch * 16;
    // stage Apk[nb..nb+16) -> lds (row 64 -> 72 pad), all 8 waves cooperate
    {
      const uint4* srcq = (const uint4*)(Ap + (size_t)nb * 768);
      for (int e = threadIdx.x; e < 1536; e += 512) {
        int r = e >> 3, col = e & 7;
        uint4 x = srcq[e];
        *(uint4*)(lds + r * 72 + col * 8) = x;
      }
    }
    short8v bf0 = *(const short8v*)(Bp + (size_t)(nb + c16) * 64 + g * 8);
    short8v bf1 = *(const short8v*)(Bp + (size_t)(nb + c16) * 64 + 32 + g * 8);
    // shape for both vtiles (sf frags loaded per chunk to bound register pressure)
    short8v sfA00 = *(const short8v*)(Sp + (size_t)(vaA +  0) * 64 + g * 8);
    short8v sfA01 = *(const short8v*)(Sp + (size_t)(vaA +  0) * 64 + 32 + g * 8);
    short8v sfA10 = *(const short8v*)(Sp + (size_t)(vaA + 16) * 64 + g * 8);
    short8v sfA11 = *(const short8v*)(Sp + (size_t)(vaA + 16) * 64 + 32 + g * 8);
    short8v sfA20 = *(const short8v*)(Sp + (size_t)(vaA + 32) * 64 + g * 8);
    short8v sfA21 = *(const short8v*)(Sp + (size_t)(vaA + 32) * 64 + 32 + g * 8);
    short8v sfB00 = *(const short8v*)(Sp + (size_t)(vaB +  0) * 64 + g * 8);
    short8v sfB01 = *(const short8v*)(Sp + (size_t)(vaB +  0) * 64 + 32 + g * 8);
    short8v sfB10 = *(const short8v*)(Sp + (size_t)(vaB + 16) * 64 + g * 8);
    short8v sfB11 = *(const short8v*)(Sp + (size_t)(vaB + 16) * 64 + 32 + g * 8);
    short8v sfB20 = *(const short8v*)(Sp + (size_t)(vaB + 32) * 64 + g * 8);
    short8v sfB21 = *(const short8v*)(Sp + (size_t)(vaB + 32) * 64 + 32 + g * 8);
    f32x4 aA0 = {0,0,0,0}, aA1 = {0,0,0,0}, aA2 = {0,0,0,0};
    f32x4 aB0 = {0,0,0,0}, aB1 = {0,0,0,0}, aB2 = {0,0,0,0};
    aA0 = __builtin_amdgcn_mfma_f32_16x16x32_bf16(sfA00, bf0, aA0, 0, 0, 0);
    aA0 = __builtin_amdgcn_mfma_f32_16x16x32_bf16(sfA01, bf1, aA0, 0, 0, 0);
    aA1 = __builtin_amdgcn_mfma_f32_16x16x32_bf16(sfA10, bf0, aA1, 0, 0, 0);
    aA1 = __builtin_amdgcn_mfma_f32_16x16x32_bf16(sfA11, bf1, aA1, 0, 0, 0);
    aA2 = __builtin_amdgcn_mfma_f32_16x16x32_bf16(sfA20, bf0, aA2, 0, 0, 0);
    aA2 = __builtin_amdgcn_mfma_f32_16x16x32_bf16(sfA21, bf1, aA2, 0, 0, 0);
    aB0 = __builtin_amdgcn_mfma_f32_16x16x32_bf16(sfB00, bf0, aB0, 0, 0, 0);
    aB0 = __builtin_amdgcn_mfma_f32_16x16x32_bf16(sfB01, bf1, aB0, 0, 0, 0);
    aB1 = __builtin_amdgcn_mfma_f32_16x16x32_bf16(sfB10, bf0, aB1, 0, 0, 0);
    aB1 = __builtin_amdgcn_mfma_f32_16x16x32_bf16(sfB11, bf1, aB1, 0, 0, 0);
    aB2 = __builtin_amdgcn_mfma_f32_16x16x32_bf16(sfB20, bf0, aB2, 0, 0, 0);
    aB2 = __builtin_amdgcn_mfma_f32_16x16x32_bf16(sfB21, bf1, aB2, 0, 0, 0);
    {
      int wb = c16 * 72;
#pragma unroll
      for (int r = 0; r < 4; r++) {
        int rho = g * 4 + r;
        vslA[wb + (rho / 3) * 4 + (rho % 3)] = bf16bits(aA0[r]);
        vslB[wb + (rho / 3) * 4 + (rho % 3)] = bf16bits(aB0[r]);
      }
#pragma unroll
      for (int r = 0; r < 4; r++) {
        int rho = 16 + g * 4 + r;
        vslA[wb + (rho / 3) * 4 + (rho % 3)] = bf16bits(aA1[r]);
        vslB[wb + (rho / 3) * 4 + (rho % 3)] = bf16bits(aB1[r]);
      }
#pragma unroll
      for (int r = 0; r < 4; r++) {
        int rho = 32 + g * 4 + r;
        vslA[wb + (rho / 3) * 4 + (rho % 3)] = bf16bits(aA2[r]);
        vslB[wb + (rho / 3) * 4 + (rho % 3)] = bf16bits(aB2[r]);
      }
    }
    __syncthreads();

    int nt_w = nb >> 4;
    size_t tbg = ((size_t)((act ? g : 0) * 64 + nt_w) * 128 + pc) * 1024;
#pragma unroll 4
    for (int np = 0; np < 16; np++) {
      const ushort* an = lds + np * 864 + c16 * 72 + g * 8;
      short8v af0 = *(const short8v*)(an);
      short8v af1 = *(const short8v*)(an + 32);
      f32x4 accA = {0,0,0,0}, accB = {0,0,0,0};
      accA = __builtin_amdgcn_mfma_f32_16x16x32_bf16(af0, wfA0, accA, 0, 0, 0);
      accA = __builtin_amdgcn_mfma_f32_16x16x32_bf16(af1, wfA1, accA, 0, 0, 0);
      accB = __builtin_amdgcn_mfma_f32_16x16x32_bf16(af0, wfB0, accB, 0, 0, 0);
      accB = __builtin_amdgcn_mfma_f32_16x16x32_bf16(af1, wfB1, accB, 0, 0, 0);
      uint2 qA = *(const uint2*)(vslA + np * 72 + c16 * 4);
      uint2 qB = *(const uint2*)(vslB + np * 72 + c16 * 4);
      float sxA = __uint_as_float((qA.x & 0xffffu) << 16);
      float syA = __uint_as_float(qA.x & 0xffff0000u);
      float szA = __uint_as_float((qA.y & 0xffffu) << 16);
      float sxB = __uint_as_float((qB.x & 0xffffu) << 16);
      float syB = __uint_as_float(qB.x & 0xffff0000u);
      float szB = __uint_as_float((qB.y & 0xffffu) << 16);
      float rA = fmaf(accA[0], sxA, fmaf(accA[1], syA, fmaf(accA[2], szA, accA[3])));
      float rB = fmaf(accB[0], sxB, fmaf(accB[1], syB, fmaf(accB[2], szB, accB[3])));
      if (pok && act) {
        vst[tbg + (size_t)((hiA * 16 + np) * 8 + e8)] = bf16bits(rA);
        vst[tbg + (size_t)((hiB * 16 + np) * 8 + e8)] = bf16bits(rB);
        out[((size_t)(nb + np) * NV + vA) * 3 + g] = rA;
        if (vB < NV) out[((size_t)(nb + np) * NV + vB) * 3 + g] = rB;
      }
    }
    __syncthreads();
  }
}

// ---------------- K_jg2: joints GEMM, 512 thr / 8 waves x 16 kc, in-block reduce -
__global__ void __launch_bounds__(512) k_jg2(
    const float* __restrict__ ws, const float* __restrict__ verts,
    float* __restrict__ jout) {
  __shared__ float red[8][48][16];
  int nt = blockIdx.x, a = blockIdx.y;
  int wv = threadIdx.x >> 6, lane = threadIdx.x & 63;
  const ushort* Jt = (const ushort*)(ws + WS_JTL);
  const ushort* Vt = (const ushort*)(ws + WS_VTL) + ((size_t)(a * 64 + nt) << 17);
  f32x4 acc0 = {0,0,0,0};
  f32x4 acc1 = {0,0,0,0};
  f32x4 acc2 = {0,0,0,0};
#pragma unroll 4
  for (int i = 0; i < 16; i++) {
    int kc = wv * 16 + i;
    short8v bfr = *(const short8v*)(Vt + ((size_t)kc << 10) + lane * 8);
    short8v af0 = *(const short8v*)(Jt + ((size_t)(0 * 128 + kc) << 9) + lane * 8);
    short8v af1 = *(const short8v*)(Jt + ((size_t)(1 * 128 + kc) << 9) + lane * 8);
    short8v af2 = *(const short8v*)(Jt + ((size_t)(2 * 128 + kc) << 9) + lane * 8);
    acc0 = __builtin_amdgcn_mfma_f32_16x16x32_bf16(af0, bfr, acc0, 0, 0, 0);
    acc1 = __builtin_amdgcn_mfma_f32_16x16x32_bf16(af1, bfr, acc1, 0, 0, 0);
    acc2 = __builtin_amdgcn_mfma_f32_16x16x32_bf16(af2, bfr, acc2, 0, 0, 0);
  }
  int hi = lane >> 4, c16 = lane & 15;
#pragma unroll
  for (int r = 0; r < 4; r++) {
    red[wv][ 0 + hi * 4 + r][c16] = acc0[r];
    red[wv][16 + hi * 4 + r][c16] = acc1[r];
    red[wv][32 + hi * 4 + r][c16] = acc2[r];
  }
  __syncthreads();
  for (int idx = threadIdx.x; idx < NJC * 16; idx += 512) {
    int j = idx >> 4, np = idx & 15;
    float s = red[0][j][np] + red[1][j][np] + red[2][j][np] + red[3][j][np] +
              red[4][j][np] + red[5][j][np] + red[6][j][np] + red[7][j][np];
    jout[(nt * 16 + np) * 117 + j * 3 + a] = s;
  }
  if (threadIdx.x < 96) {
    int e = threadIdx.x >> 4, np = threadIdx.x & 15;
    int n = nt * 16 + np;
    jout[n * 117 + 99 + e * 3 + a] = verts[(size_t)n * NV3 + EXTRA_IDS[e] * 3 + a];
  }
}

extern "C" void kernel_launch(void* const* d_in, const int* in_sizes, int n_in,
                              void* d_out, int out_size, void* d_ws, size_t ws_size,
                              hipStream_t stream) {
  const float* beta       = (const float*)d_in[0];
  const float* theta      = (const float*)d_in[1];
  const float* trans      = (const float*)d_in[2];
  const float* bls        = (const float*)d_in[3];
  const float* shapedirs  = (const float*)d_in[4];
  const float* v_template = (const float*)d_in[5];
  const float* Jreg       = (const float*)d_in[6];
  // d_in[7] = posedirs : multiplied by zeros in the reference -> unused
  const float* weights    = (const float*)d_in[8];
  float* out = (float*)d_out;
  float* ws  = (float*)d_ws;
  float* jout = out + (size_t)NN * NV3;

  k_prep<<<PREP_SJ_BLOCKS + PREP_SD_BLOCKS + PREP_PK_BLOCKS + PREP_VZ_BLOCKS,
           256, 0, stream>>>(Jreg, weights, beta, shapedirs, v_template, ws);
  k_pose<<<64, 256, 0, stream>>>(beta, theta, bls, trans, ws);
  dim3 gsv(16, 32);
  k_sv<<<gsv, 512, 0, stream>>>(ws, (ushort*)(ws + WS_VTL), out);
  dim3 gj(64, 3);
  k_jg2<<<gj, 512, 0, stream>>>(ws, out, jout);
}

// Round 11
// 70.217 us; speedup vs baseline: 1.0946x; 1.0946x over previous
//
#include <hip/hip_runtime.h>
#include <hip/hip_bf16.h>

#define NV 3889
#define NV3 11667
#define NVP 3904      // ceil(NV/16)*16
#define NVAP 11712    // NVP*3
#define NJC 33        // joints in chain
#define NBB 41        // betas
#define NN 1024       // batch

__device__ const int EXTRA_IDS[6] = {1863, 26, 2124, 150, 3055, 1097};

// ws layout (float offsets)  [R0 layout — verified]
#define WS_SJ    0          // f32 [42][99] (pad)    = 4160
#define WS_WPK   4160       // bf16[3904][64]        = 124928 fl
#define WS_SDPK  129088     // bf16[11712][64]       = 374784 fl
#define WS_BPK   503872     // bf16[1024][64]        = 32768 fl
#define WS_APK   536640     // bf16[1024][12][64]    = 393216 fl
#define WS_JTL   929856     // bf16 tiled Jreg [3*128][64][8]          = 98304 fl
#define WS_VTL   1028160    // bf16 tiled vsT [3*64 planes][128][1024] = 12582912 fl
#define WS_SJP   13611072   // f32 [672][100] SJ partials = 67200 fl
// end: 13678272 floats (~55 MB)

typedef __attribute__((ext_vector_type(8))) short short8v;
typedef __attribute__((ext_vector_type(4))) float f32x4;

__device__ __forceinline__ ushort bf16bits(float x) {
  __hip_bfloat16 h = __float2bfloat16(x);
  return *reinterpret_cast<ushort*>(&h);
}

// ---------------- K_prep: vectorized packing + chunked SJ + VTL tail-zero ------
// grid = 672 (SJ) + 366 (SDPK transpose) + 250 (WPK/BPK/JTL) + 576 (VTL zero)
#define PREP_SJ_BLOCKS 672
#define PREP_SD_BLOCKS 366
#define PREP_PK_BLOCKS 250
#define PREP_VZ_BLOCKS 576
__global__ void __launch_bounds__(256) k_prep(
    const float* __restrict__ Jreg, const float* __restrict__ w,
    const float* __restrict__ beta, const float* __restrict__ sd,
    const float* __restrict__ vt, float* __restrict__ ws) {
  int bx = blockIdx.x;
  int t = threadIdx.x;
  if (bx < PREP_SJ_BLOCKS) {
    // ---- SJ partials (chunked: 42 b x 16 chunks); float3 vector loads ----
    int bid2 = bx;                    // 0..671
    int b = bid2 >> 4, c = bid2 & 15;
    const float* src = (b < NBB) ? (sd + (size_t)b * NV3) : vt;
    const float3* s3 = (const float3*)src;   // 12B loads (4B aligned)
    int dv = t / 33, j = t - dv * 33;
    float p0 = 0.f, p1 = 0.f, p2 = 0.f;
    int vbase = c * 244;
    int vend = vbase + 244;
    if (vend > NV) vend = NV;
    if (t < 231) {
      for (int v0 = vbase; v0 < vend; v0 += 7) {
        int v = v0 + dv;
        if (v < vend) {
          float jr = Jreg[v0 * 33 + t];   // contiguous across threads
          float3 s = s3[v];
          p0 += s.x * jr;
          p1 += s.y * jr;
          p2 += s.z * jr;
        }
      }
    }
    __shared__ float sred[7][33][3];
    if (t < 231) { sred[dv][j][0] = p0; sred[dv][j][1] = p1; sred[dv][j][2] = p2; }
    __syncthreads();
    if (t < 99) {
      int jj = t / 3, aa = t - jj * 3;
      float s = 0.f;
#pragma unroll
      for (int d = 0; d < 7; d++) s += sred[d][jj][aa];
      ws[WS_SJP + bid2 * 100 + t] = s;
    }
    return;
  }
  bx -= PREP_SJ_BLOCKS;
  if (bx < PREP_SD_BLOCKS) {
    // ---- SDPK: coalesced read of sd rows -> LDS transpose -> packed store ----
    __shared__ ushort tl[32 * 50];    // 32 va x 50(pad) bs
    int va0 = bx * 32;
    for (int i = t; i < 42 * 32; i += 256) {
      int bs = i >> 5, off = i & 31;
      int va = va0 + off;
      float v = 0.f;
      if (va < NV3) v = (bs < NBB) ? sd[(size_t)bs * NV3 + va] : vt[va];
      tl[off * 50 + bs] = bf16bits(v);
    }
    __syncthreads();
    int va_l = t >> 3, ch = t & 7;    // 32 va x 8 chunks = 256 threads
    short8v pk;
#pragma unroll
    for (int e = 0; e < 8; e++) {
      int bs = ch * 8 + e;
      pk[e] = (bs < 42) ? (short)tl[va_l * 50 + bs] : (short)0;
    }
    *(short8v*)((ushort*)(ws + WS_SDPK) + ((size_t)(va0 + va_l) * 64 + ch * 8)) = pk;
    return;
  }
  bx -= PREP_SD_BLOCKS;
  if (bx < PREP_PK_BLOCKS) {
    int id8 = bx * 256 + t;
    const int R1 = NVP * 64 / 8;       // 31232  Wpk
    const int R3 = NN * 64 / 8;        // 8192   bpk
    short8v pk;
    if (id8 < R1) {
      int u = id8 * 8;
      int v = u >> 6, j0 = u & 63;
#pragma unroll
      for (int e = 0; e < 8; e++) {
        int j = j0 + e;
        float val;
        if (j < NJC)      val = (v < NV) ? w[v * NJC + j] : 0.f;
        else if (j == 41) val = 1.f;               // trans row
        else              val = 0.f;
        pk[e] = (short)bf16bits(val);
      }
      *(short8v*)((ushort*)(ws + WS_WPK) + u) = pk;
      return;
    }
    id8 -= R1;
    if (id8 < R3) {
      int u = id8 * 8;
      int n = u >> 6, bs0 = u & 63;
#pragma unroll
      for (int e = 0; e < 8; e++) {
        int bs = bs0 + e;
        float val = (bs < NBB) ? beta[n * NBB + bs] : (bs == NBB ? 1.f : 0.f);
        pk[e] = (short)bf16bits(val);
      }
      *(short8v*)((ushort*)(ws + WS_BPK) + u) = pk;
      return;
    }
    id8 -= R3;
    {
      // JregTl[tile=jt*128+kc][lane][e]; A-frag: row=lane&15, k=(lane>>4)*8+e
      int u = id8 * 8;                 // id8 < 24576
      int tile = u >> 9, lane = (u >> 3) & 63;
      int jt = tile >> 7, kc = tile & 127;
      int j = jt * 16 + (lane & 15);
      int vb = kc * 32 + ((lane >> 4) << 3);
#pragma unroll
      for (int e = 0; e < 8; e++) {
        int v = vb + e;
        float val = (j < NJC && v < NV) ? Jreg[v * NJC + j] : 0.f;
        pk[e] = (short)bf16bits(val);
      }
      *(short8v*)((ushort*)(ws + WS_JTL) + u) = pk;
      return;
    }
  }
  bx -= PREP_PK_BLOCKS;
  {
    // ---- VTL tail-zero: rows 122..127 of each [128][1024] plane ----
    int id8 = bx * 256 + t;            // [0, 147456)
    int plane = id8 / 768;             // 0..191
    int rem8 = id8 - plane * 768;      // 0..767
    short8v z = {0, 0, 0, 0, 0, 0, 0, 0};
    *(short8v*)((ushort*)(ws + WS_VTL) +
                ((size_t)plane * 131072 + 124928 + rem8 * 8)) = z;
  }
}

// ---------------- K_sjr: reduce 16 chunk-partials -> SJ ----------------
__global__ void __launch_bounds__(256) k_sjr(float* __restrict__ ws) {
  int idx = blockIdx.x * 256 + threadIdx.x;
  if (idx >= 42 * 99) return;
  int b = idx / 99, k = idx - b * 99;
  float s = 0.f;
#pragma unroll
  for (int c = 0; c < 16; c++) s += ws[WS_SJP + (b * 16 + c) * 100 + k];
  ws[WS_SJ + idx] = s;
}

// ---------------- K_pose: J blend + rodrigues + chain -> Apk (bf16, 12x64) ------
__device__ __forceinline__ void get_scal(int r, float e0, float e1, float e2, float e3,
                                         float s[3]) {
  bool leg  = (r >= 7 && r <= 14) || (r >= 17 && r <= 24);
  bool tail = (r >= 25 && r <= 31);
  s[0] = leg ? e1 : (tail ? e2 : 1.f);
  s[1] = leg ? e1 : (tail ? e3 : 1.f);
  s[2] = leg ? e0 : (tail ? e3 : 1.f);
}

__device__ __forceinline__ void rodrigues(const float* th, float R[9]) {
  float tx = th[0], ty = th[1], tz = th[2];
  float ax = tx + 1e-8f, ay = ty + 1e-8f, az = tz + 1e-8f;
  float angle = sqrtf(ax * ax + ay * ay + az * az);
  float inv = 1.f / angle;
  float rx = tx * inv, ry = ty * inv, rz = tz * inv;
  float c = cosf(angle), s = sinf(angle), o = 1.f - c;
  R[0] = c + o * rx * rx;      R[1] = o * rx * ry - s * rz; R[2] = o * rx * rz + s * ry;
  R[3] = o * rx * ry + s * rz; R[4] = c + o * ry * ry;      R[5] = o * ry * rz - s * rx;
  R[6] = o * rx * rz - s * ry; R[7] = o * ry * rz + s * rx; R[8] = c + o * rz * rz;
}

__global__ void __launch_bounds__(128) k_pose(
    const float* __restrict__ beta, const float* __restrict__ theta,
    const float* __restrict__ bls, const float* __restrict__ trans,
    float* __restrict__ ws) {
  int n = blockIdx.x, t = threadIdx.x;
  __shared__ float Jsh[99];
  __shared__ float Bsh[NJC * 12];
  __shared__ float Ash[NJC * 12];
  if (t < 99) {
    const float* SJ = ws + WS_SJ;
    float acc = SJ[NBB * 99 + t];
    const float* bn = beta + n * NBB;
#pragma unroll
    for (int b = 0; b < NBB; b++) acc += bn[b] * SJ[b * 99 + t];
    Jsh[t] = acc;
  }
  __syncthreads();
  if (t < NJC) {
    float R[9];
    rodrigues(theta + n * 105 + t * 3, R);
    float* B = Bsh + t * 12;
    if (t == 0) {
      B[0] = R[0]; B[1] = R[1]; B[2]  = R[2]; B[3]  = Jsh[0];
      B[4] = R[3]; B[5] = R[4]; B[6]  = R[5]; B[7]  = Jsh[1];
      B[8] = R[6]; B[9] = R[7]; B[10] = R[8]; B[11] = Jsh[2];
    } else {
      float e0 = expf(bls[n * 6 + 0]), e1 = expf(bls[n * 6 + 1]);
      float e2 = expf(bls[n * 6 + 2]), e3 = expf(bls[n * 6 + 3]);
      float si[3], sp[3];
      get_scal(t, e0, e1, e2, e3, si);
      get_scal(t - 1, e0, e1, e2, e3, sp);
#pragma unroll
      for (int r = 0; r < 3; r++) {
        float inv = 1.f / sp[r];
#pragma unroll
        for (int cc = 0; cc < 3; cc++) B[r * 4 + cc] = R[r * 3 + cc] * si[cc] * inv;
        B[r * 4 + 3] = Jsh[t * 3 + r] - Jsh[(t - 1) * 3 + r];
      }
    }
  }
  __syncthreads();
  if (t == 0) {
    float G[12];
#pragma unroll
    for (int k = 0; k < 12; k++) G[k] = Bsh[k];
#pragma unroll
    for (int i = 0; i < NJC; i++) {
      if (i > 0) {
        float b[12];
#pragma unroll
        for (int k = 0; k < 12; k++) b[k] = Bsh[i * 12 + k];
        float Gn[12];
#pragma unroll
        for (int r = 0; r < 3; r++) {
#pragma unroll
          for (int cc = 0; cc < 4; cc++) {
            float acc = G[r * 4 + 0] * b[0 * 4 + cc] + G[r * 4 + 1] * b[1 * 4 + cc] +
                        G[r * 4 + 2] * b[2 * 4 + cc];
            if (cc == 3) acc += G[r * 4 + 3];
            Gn[r * 4 + cc] = acc;
          }
        }
#pragma unroll
        for (int k = 0; k < 12; k++) G[k] = Gn[k];
      }
      float jx = Jsh[i * 3 + 0], jy = Jsh[i * 3 + 1], jz = Jsh[i * 3 + 2];
      float* Ai = Ash + i * 12;
      Ai[0] = G[0]; Ai[1] = G[1]; Ai[2]  = G[2];
      Ai[3] = G[3] - (G[0] * jx + G[1] * jy + G[2] * jz);
      Ai[4] = G[4]; Ai[5] = G[5]; Ai[6]  = G[6];
      Ai[7] = G[7] - (G[4] * jx + G[5] * jy + G[6] * jz);
      Ai[8] = G[8]; Ai[9] = G[9]; Ai[10] = G[10];
      Ai[11] = G[11] - (G[8] * jx + G[9] * jy + G[10] * jz);
    }
  }
  __syncthreads();
  // Apk[n][c 0..11][j 0..63]; A_op[c][j] = A_n[j][c]; col 41 of rows 3/7/11 = trans
  __hip_bfloat16* apk = (__hip_bfloat16*)(ws + WS_APK) + (size_t)n * 768;
  for (int i = t; i < 768; i += 128) {
    int c = i >> 6, j = i & 63;
    float val = 0.f;
    if (j < NJC)                           val = Ash[j * 12 + c];
    else if (j == 41 && (c & 3) == 3)      val = trans[n * 3 + (c >> 2)];
    apk[i] = __float2bfloat16(val);
  }
}

// ---------------- K_sv: 512 threads, 8 waves share Ash; VT=2; 2 chunks/block ----
// [R0-verified structure: 2 barriers/chunk, vst bf16 tile out for k_jg2]
#define ASH_USH (16 * 12 * 72)        // 13824 ushorts (27.6 KB)
#define VSL2_USH (2 * 16 * 72)        // 2304 ushorts per wave (2 vtiles)

__global__ void __launch_bounds__(512, 4) k_sv(
    const float* __restrict__ ws, ushort* __restrict__ vst,
    float* __restrict__ out) {
  __shared__ __align__(16) ushort lds[ASH_USH + 8 * VSL2_USH];   // 64.5 KB
  int wv = threadIdx.x >> 6, lane = threadIdx.x & 63;
  int g = lane >> 4, c16 = lane & 15;
  int p = blockIdx.x * 8 + wv;         // pair index 0..127
  int pc = p < 122 ? p : 121;
  bool pok = p < 122;
  int vtA = pc * 2, vtB = vtA + 1;
  int vA = vtA * 16 + c16, vB = vtB * 16 + c16;
  int nb0 = blockIdx.y * 32;
  const ushort* Wp = (const ushort*)(ws + WS_WPK);
  const ushort* Sp = (const ushort*)(ws + WS_SDPK);
  const ushort* Bp = (const ushort*)(ws + WS_BPK);
  const ushort* Ap = (const ushort*)(ws + WS_APK);

  // loop-invariant fragments
  short8v wfA0 = *(const short8v*)(Wp + vA * 64 + g * 8);
  short8v wfA1 = *(const short8v*)(Wp + vA * 64 + 32 + g * 8);
  short8v wfB0 = *(const short8v*)(Wp + vB * 64 + g * 8);
  short8v wfB1 = *(const short8v*)(Wp + vB * 64 + 32 + g * 8);
  int vaA = vtA * 48 + c16, vaB = vtB * 48 + c16;

  ushort* vslA = lds + ASH_USH + wv * VSL2_USH;
  ushort* vslB = vslA + 1152;
  bool act = g < 3;
  int hiA = c16 >> 3, hiB = 2 + (c16 >> 3), e8 = c16 & 7;

#pragma unroll 1
  for (int ch = 0; ch < 2; ch++) {
    int nb = nb0 + ch * 16;
    // stage Apk[nb..nb+16) -> lds (row 64 -> 72 pad), all 8 waves cooperate
    {
      const uint4* srcq = (const uint4*)(Ap + (size_t)nb * 768);
      for (int e = threadIdx.x; e < 1536; e += 512) {
        int r = e >> 3, col = e & 7;
        uint4 x = srcq[e];
        *(uint4*)(lds + r * 72 + col * 8) = x;
      }
    }
    short8v bf0 = *(const short8v*)(Bp + (size_t)(nb + c16) * 64 + g * 8);
    short8v bf1 = *(const short8v*)(Bp + (size_t)(nb + c16) * 64 + 32 + g * 8);
    // shape for both vtiles (sf frags loaded per chunk to bound register pressure)
    short8v sfA00 = *(const short8v*)(Sp + (size_t)(vaA +  0) * 64 + g * 8);
    short8v sfA01 = *(const short8v*)(Sp + (size_t)(vaA +  0) * 64 + 32 + g * 8);
    short8v sfA10 = *(const short8v*)(Sp + (size_t)(vaA + 16) * 64 + g * 8);
    short8v sfA11 = *(const short8v*)(Sp + (size_t)(vaA + 16) * 64 + 32 + g * 8);
    short8v sfA20 = *(const short8v*)(Sp + (size_t)(vaA + 32) * 64 + g * 8);
    short8v sfA21 = *(const short8v*)(Sp + (size_t)(vaA + 32) * 64 + 32 + g * 8);
    short8v sfB00 = *(const short8v*)(Sp + (size_t)(vaB +  0) * 64 + g * 8);
    short8v sfB01 = *(const short8v*)(Sp + (size_t)(vaB +  0) * 64 + 32 + g * 8);
    short8v sfB10 = *(const short8v*)(Sp + (size_t)(vaB + 16) * 64 + g * 8);
    short8v sfB11 = *(const short8v*)(Sp + (size_t)(vaB + 16) * 64 + 32 + g * 8);
    short8v sfB20 = *(const short8v*)(Sp + (size_t)(vaB + 32) * 64 + g * 8);
    short8v sfB21 = *(const short8v*)(Sp + (size_t)(vaB + 32) * 64 + 32 + g * 8);
    f32x4 aA0 = {0,0,0,0}, aA1 = {0,0,0,0}, aA2 = {0,0,0,0};
    f32x4 aB0 = {0,0,0,0}, aB1 = {0,0,0,0}, aB2 = {0,0,0,0};
    aA0 = __builtin_amdgcn_mfma_f32_16x16x32_bf16(sfA00, bf0, aA0, 0, 0, 0);
    aA0 = __builtin_amdgcn_mfma_f32_16x16x32_bf16(sfA01, bf1, aA0, 0, 0, 0);
    aA1 = __builtin_amdgcn_mfma_f32_16x16x32_bf16(sfA10, bf0, aA1, 0, 0, 0);
    aA1 = __builtin_amdgcn_mfma_f32_16x16x32_bf16(sfA11, bf1, aA1, 0, 0, 0);
    aA2 = __builtin_amdgcn_mfma_f32_16x16x32_bf16(sfA20, bf0, aA2, 0, 0, 0);
    aA2 = __builtin_amdgcn_mfma_f32_16x16x32_bf16(sfA21, bf1, aA2, 0, 0, 0);
    aB0 = __builtin_amdgcn_mfma_f32_16x16x32_bf16(sfB00, bf0, aB0, 0, 0, 0);
    aB0 = __builtin_amdgcn_mfma_f32_16x16x32_bf16(sfB01, bf1, aB0, 0, 0, 0);
    aB1 = __builtin_amdgcn_mfma_f32_16x16x32_bf16(sfB10, bf0, aB1, 0, 0, 0);
    aB1 = __builtin_amdgcn_mfma_f32_16x16x32_bf16(sfB11, bf1, aB1, 0, 0, 0);
    aB2 = __builtin_amdgcn_mfma_f32_16x16x32_bf16(sfB20, bf0, aB2, 0, 0, 0);
    aB2 = __builtin_amdgcn_mfma_f32_16x16x32_bf16(sfB21, bf1, aB2, 0, 0, 0);
    {
      int wb = c16 * 72;
#pragma unroll
      for (int r = 0; r < 4; r++) {
        int rho = g * 4 + r;
        vslA[wb + (rho / 3) * 4 + (rho % 3)] = bf16bits(aA0[r]);
        vslB[wb + (rho / 3) * 4 + (rho % 3)] = bf16bits(aB0[r]);
      }
#pragma unroll
      for (int r = 0; r < 4; r++) {
        int rho = 16 + g * 4 + r;
        vslA[wb + (rho / 3) * 4 + (rho % 3)] = bf16bits(aA1[r]);
        vslB[wb + (rho / 3) * 4 + (rho % 3)] = bf16bits(aB1[r]);
      }
#pragma unroll
      for (int r = 0; r < 4; r++) {
        int rho = 32 + g * 4 + r;
        vslA[wb + (rho / 3) * 4 + (rho % 3)] = bf16bits(aA2[r]);
        vslB[wb + (rho / 3) * 4 + (rho % 3)] = bf16bits(aB2[r]);
      }
    }
    __syncthreads();

    int nt_w = nb >> 4;
    size_t tbg = ((size_t)((act ? g : 0) * 64 + nt_w) * 128 + pc) * 1024;
#pragma unroll 4
    for (int np = 0; np < 16; np++) {
      const ushort* an = lds + np * 864 + c16 * 72 + g * 8;
      short8v af0 = *(const short8v*)(an);
      short8v af1 = *(const short8v*)(an + 32);
      f32x4 accA = {0,0,0,0}, accB = {0,0,0,0};
      accA = __builtin_amdgcn_mfma_f32_16x16x32_bf16(af0, wfA0, accA, 0, 0, 0);
      accA = __builtin_amdgcn_mfma_f32_16x16x32_bf16(af1, wfA1, accA, 0, 0, 0);
      accB = __builtin_amdgcn_mfma_f32_16x16x32_bf16(af0, wfB0, accB, 0, 0, 0);
      accB = __builtin_amdgcn_mfma_f32_16x16x32_bf16(af1, wfB1, accB, 0, 0, 0);
      uint2 qA = *(const uint2*)(vslA + np * 72 + c16 * 4);
      uint2 qB = *(const uint2*)(vslB + np * 72 + c16 * 4);
      float sxA = __uint_as_float((qA.x & 0xffffu) << 16);
      float syA = __uint_as_float(qA.x & 0xffff0000u);
      float szA = __uint_as_float((qA.y & 0xffffu) << 16);
      float sxB = __uint_as_float((qB.x & 0xffffu) << 16);
      float syB = __uint_as_float(qB.x & 0xffff0000u);
      float szB = __uint_as_float((qB.y & 0xffffu) << 16);
      float rA = fmaf(accA[0], sxA, fmaf(accA[1], syA, fmaf(accA[2], szA, accA[3])));
      float rB = fmaf(accB[0], sxB, fmaf(accB[1], syB, fmaf(accB[2], szB, accB[3])));
      if (pok && act) {
        vst[tbg + (size_t)((hiA * 16 + np) * 8 + e8)] = bf16bits(rA);
        vst[tbg + (size_t)((hiB * 16 + np) * 8 + e8)] = bf16bits(rB);
        out[((size_t)(nb + np) * NV + vA) * 3 + g] = rA;
        if (vB < NV) out[((size_t)(nb + np) * NV + vB) * 3 + g] = rB;
      }
    }
    __syncthreads();
  }
}

// ---------------- K_jg2: joints GEMM, 512 thr / 8 waves x 16 kc, in-block reduce -
__global__ void __launch_bounds__(512) k_jg2(
    const float* __restrict__ ws, const float* __restrict__ verts,
    float* __restrict__ jout) {
  __shared__ float red[8][48][16];
  int nt = blockIdx.x, a = blockIdx.y;
  int wv = threadIdx.x >> 6, lane = threadIdx.x & 63;
  const ushort* Jt = (const ushort*)(ws + WS_JTL);
  const ushort* Vt = (const ushort*)(ws + WS_VTL) + ((size_t)(a * 64 + nt) << 17);
  f32x4 acc0 = {0,0,0,0};
  f32x4 acc1 = {0,0,0,0};
  f32x4 acc2 = {0,0,0,0};
#pragma unroll 4
  for (int i = 0; i < 16; i++) {
    int kc = wv * 16 + i;
    short8v bfr = *(const short8v*)(Vt + ((size_t)kc << 10) + lane * 8);
    short8v af0 = *(const short8v*)(Jt + ((size_t)(0 * 128 + kc) << 9) + lane * 8);
    short8v af1 = *(const short8v*)(Jt + ((size_t)(1 * 128 + kc) << 9) + lane * 8);
    short8v af2 = *(const short8v*)(Jt + ((size_t)(2 * 128 + kc) << 9) + lane * 8);
    acc0 = __builtin_amdgcn_mfma_f32_16x16x32_bf16(af0, bfr, acc0, 0, 0, 0);
    acc1 = __builtin_amdgcn_mfma_f32_16x16x32_bf16(af1, bfr, acc1, 0, 0, 0);
    acc2 = __builtin_amdgcn_mfma_f32_16x16x32_bf16(af2, bfr, acc2, 0, 0, 0);
  }
  int hi = lane >> 4, c16 = lane & 15;
#pragma unroll
  for (int r = 0; r < 4; r++) {
    red[wv][ 0 + hi * 4 + r][c16] = acc0[r];
    red[wv][16 + hi * 4 + r][c16] = acc1[r];
    red[wv][32 + hi * 4 + r][c16] = acc2[r];
  }
  __syncthreads();
  for (int idx = threadIdx.x; idx < NJC * 16; idx += 512) {
    int j = idx >> 4, np = idx & 15;
    float s = red[0][j][np] + red[1][j][np] + red[2][j][np] + red[3][j][np] +
              red[4][j][np] + red[5][j][np] + red[6][j][np] + red[7][j][np];
    jout[(nt * 16 + np) * 117 + j * 3 + a] = s;
  }
  if (threadIdx.x < 96) {
    int e = threadIdx.x >> 4, np = threadIdx.x & 15;
    int n = nt * 16 + np;
    jout[n * 117 + 99 + e * 3 + a] = verts[(size_t)n * NV3 + EXTRA_IDS[e] * 3 + a];
  }
}

extern "C" void kernel_launch(void* const* d_in, const int* in_sizes, int n_in,
                              void* d_out, int out_size, void* d_ws, size_t ws_size,
                              hipStream_t stream) {
  const float* beta       = (const float*)d_in[0];
  const float* theta      = (const float*)d_in[1];
  const float* trans      = (const float*)d_in[2];
  const float* bls        = (const float*)d_in[3];
  const float* shapedirs  = (const float*)d_in[4];
  const float* v_template = (const float*)d_in[5];
  const float* Jreg       = (const float*)d_in[6];
  // d_in[7] = posedirs : multiplied by zeros in the reference -> unused
  const float* weights    = (const float*)d_in[8];
  float* out = (float*)d_out;
  float* ws  = (float*)d_ws;
  float* jout = out + (size_t)NN * NV3;

  k_prep<<<PREP_SJ_BLOCKS + PREP_SD_BLOCKS + PREP_PK_BLOCKS + PREP_VZ_BLOCKS,
           256, 0, stream>>>(Jreg, weights, beta, shapedirs, v_template, ws);
  k_sjr<<<17, 256, 0, stream>>>(ws);
  k_pose<<<NN, 128, 0, stream>>>(beta, theta, bls, trans, ws);
  dim3 gsv(16, 32);
  k_sv<<<gsv, 512, 0, stream>>>(ws, (ushort*)(ws + WS_VTL), out);
  dim3 gj(64, 3);
  k_jg2<<<gj, 512, 0, stream>>>(ws, out, jout);
}